// Round 5
// baseline (405.841 us; speedup 1.0000x reference)
//
#include <hip/hip_runtime.h>

#define HDIM 32
#define NBINS 512   // lengths occupy bins 0..256; padded to pow2 for the scan

typedef _Float16 f16x8 __attribute__((ext_vector_type(8)));
typedef float f32x16 __attribute__((ext_vector_type(16)));
typedef unsigned int u32x4 __attribute__((ext_vector_type(4)));
#define MFMA32(A,B,C) __builtin_amdgcn_mfma_f32_32x32x16_f16((A),(B),(C),0,0,0)

// pack two f32 -> one u32 of 2 f16 (v_cvt_pkrtz_f16_f32, single VALU op)
__device__ __forceinline__ unsigned int pk_f16(float a, float b) {
    return __builtin_bit_cast(unsigned int, __builtin_amdgcn_cvt_pkrtz(a, b));
}
// v_permlane32_swap_b32 (verified semantics via the passing RNN)
__device__ __forceinline__ void pl32swap(unsigned int& a, unsigned int& b) {
    asm("v_permlane32_swap_b32 %0, %1" : "+v"(a), "+v"(b));
}

// tanh via Lambert continued-fraction [3/2] Pade + med3 clamp.
// max |err| ~1.3e-3 (near z=3.7 where the clamp engages); ONE trans op
// (v_rcp) instead of two (v_exp + v_rcp) -- the two transcendentals were
// ~83% of the round-4 RNN step issue. den >= 945 > 0 always; for |z| past
// the crossing the rational is monotonically > 1, so med3 saturates exactly.
__device__ __forceinline__ float pade_tanh(float z) {
    const float u = z * z;
    const float nump = fmaf(u, u + 105.0f, 945.0f);
    const float den  = fmaf(u, fmaf(u, 15.0f, 420.0f), 945.0f);
    const float r = z * nump * __builtin_amdgcn_rcpf(den);
    return __builtin_amdgcn_fmed3f(r, -1.0f, 1.0f);
}

#define PIN16(a) asm("" : "+v"(a[0]),"+v"(a[1]),"+v"(a[2]),"+v"(a[3]), \
                         "+v"(a[4]),"+v"(a[5]),"+v"(a[6]),"+v"(a[7]), \
                         "+v"(a[8]),"+v"(a[9]),"+v"(a[10]),"+v"(a[11]), \
                         "+v"(a[12]),"+v"(a[13]),"+v"(a[14]),"+v"(a[15]))
#define PIN8(a)  asm("" : "+v"(a[0]),"+v"(a[1]),"+v"(a[2]),"+v"(a[3]), \
                         "+v"(a[4]),"+v"(a[5]),"+v"(a[6]),"+v"(a[7]))

// ---- length-bucketing: counting sort into a permutation (DESCENDING) ----
__global__ __launch_bounds__(256) void hist_kernel(
    const int* __restrict__ l, int* __restrict__ cnt, int nseq)
{
    __shared__ int hc[NBINS];
    for (int k = threadIdx.x; k < NBINS; k += blockDim.x) hc[k] = 0;
    __syncthreads();
    for (int i = blockIdx.x * blockDim.x + threadIdx.x; i < nseq;
         i += gridDim.x * blockDim.x)
        atomicAdd(&hc[l[i]], 1);
    __syncthreads();
    for (int k = threadIdx.x; k < NBINS; k += blockDim.x)
        if (hc[k]) atomicAdd(&cnt[k], hc[k]);
}

// off[t] = sum_{k>t} cnt[k]  (exclusive SUFFIX sum -> longest lengths first)
__global__ __launch_bounds__(NBINS) void scan_kernel(
    const int* __restrict__ cnt, int* __restrict__ off)
{
    __shared__ int sc[NBINS];
    int t = threadIdx.x;
    int v0 = cnt[t];
    sc[t] = v0;
    __syncthreads();
    for (int d = 1; d < NBINS; d <<= 1) {
        int v = (t + d < NBINS) ? sc[t + d] : 0;
        __syncthreads();
        sc[t] += v;
        __syncthreads();
    }
    off[t] = sc[t] - v0;          // strictly-greater suffix sum
}

// Block-aggregated scatter: LDS histogram per block, ONE global atomic per
// touched bin to reserve a range, then LDS cursors for local ranks.
__global__ __launch_bounds__(256) void scatter_kernel(
    const int* __restrict__ l, int* __restrict__ off,
    int* __restrict__ perm, int nseq)
{
    __shared__ int lcur[NBINS];
    const int chunk = (nseq + gridDim.x - 1) / gridDim.x;
    const int lo = blockIdx.x * chunk;
    const int hi = min(nseq, lo + chunk);
    for (int k = threadIdx.x; k < NBINS; k += blockDim.x) lcur[k] = 0;
    __syncthreads();
    for (int i = lo + threadIdx.x; i < hi; i += blockDim.x)
        atomicAdd(&lcur[l[i]], 1);
    __syncthreads();
    for (int k = threadIdx.x; k < NBINS; k += blockDim.x) {
        int c = lcur[k];
        lcur[k] = c ? atomicAdd(&off[k], c) : 0;   // global base for this block
    }
    __syncthreads();
    for (int i = lo + threadIdx.x; i < hi; i += blockDim.x) {
        int p = atomicAdd(&lcur[l[i]], 1);         // LDS cursor = base + rank
        perm[p] = i;
    }
}

// ---- RNN: wave = 32 (length-matched) sequences, MFMA 32x32x16 f16 ----
// Lane: n = lane&31 (seq/column), half = lane>>5.
// A frag f: A[m=n][k=8*half+j] -> W_hh[n*32 + 16f + 8*half + j]
// B frag f: B[k][n=lane&31], k = 16f + 8*half + j -> h[k]
// C/D: col=lane&31, row=(r&3)+8*(r>>2)+4*half   [verified mapping]
//
// Round-5 changes:
//  * REFLECTED-PAIR BALANCE: round-4 counters showed time-avg occupancy
//    2.6/4 waves per SIMD and VALUBusy 67% -- desc-sorted round-robin puts
//    one long + several short waves on each SIMD; shorts retire and the
//    long wave limps alone, latency-bound. Now each wave runs group p
//    (long) then group ngroups-1-p (short): every wave's total step count
//    ~= const, all waves retire together. Dispatch-order-agnostic.
//  * 1-TRANS TANH: pade_tanh (see above). The exp2+rcp pair was ~83% of
//    per-step issue at the observed trans rate; now one rcp + 7 cheap VALU.
//    S=2*log2(e) weight folding removed (acc = true pre-activation).
__global__ __launch_bounds__(128, 4) void rnn_kernel(
    const float* __restrict__ hin, const int* __restrict__ l,
    const int* __restrict__ perm,
    const float* __restrict__ W_ih, const float* __restrict__ W_hh,
    const float* __restrict__ b_ih, const float* __restrict__ b_hh,
    _Float16* __restrict__ emb, int nseq, int tmax)
{
    const int lane = threadIdx.x & 63;
    const int n    = lane & 31;
    const int half = lane >> 5;

    const int ngroups = (nseq + 31) >> 5;
    const int npairs  = (ngroups + 1) >> 1;
    const int p = blockIdx.x * 2 + (threadIdx.x >> 6);
    if (p >= npairs) return;

    // persistent A fragments (W_hh in f16), pinned; shared by both groups
    unsigned int qw[8];
    {
        f16x8 w[2];
        #pragma unroll
        for (int f = 0; f < 2; ++f)
            #pragma unroll
            for (int j = 0; j < 8; ++j)
                w[f][j] = (_Float16)W_hh[n * 32 + 16 * f + 8 * half + j];
        u32x4 qa = __builtin_bit_cast(u32x4, w[0]);
        u32x4 qb = __builtin_bit_cast(u32x4, w[1]);
        #pragma unroll
        for (int c = 0; c < 4; ++c) { qw[c] = qa[c]; qw[4 + c] = qb[c]; }
    }
    PIN8(qw);
    const f16x8 WA = __builtin_bit_cast(f16x8, (u32x4){qw[0], qw[1], qw[2], qw[3]});
    const f16x8 WB = __builtin_bit_cast(f16x8, (u32x4){qw[4], qw[5], qw[6], qw[7]});

    // input-path MFMA A-fragment: A[m][0] = W_ih[m] on half0, else zero
    unsigned int xaw = half ? 0u : pk_f16(W_ih[n], 0.0f);
    unsigned int zz[3] = {0u, 0u, 0u};
    asm("" : "+v"(xaw), "+v"(zz[0]), "+v"(zz[1]), "+v"(zz[2]));
    const f16x8 XA = __builtin_bit_cast(f16x8, (u32x4){xaw, zz[0], zz[1], zz[2]});

    // bias as the f32 MFMA C operand (exact path)
    float bv[16];
    #pragma unroll
    for (int r = 0; r < 16; ++r) {
        const int row = (r & 3) + 8 * (r >> 2) + 4 * half;
        bv[r] = b_ih[row] + b_hh[row];
    }
    PIN16(bv);
    f32x16 bC;
    #pragma unroll
    for (int r = 0; r < 16; ++r) bC[r] = bv[r];

    #pragma unroll 1
    for (int part = 0; part < 2; ++part) {
        const int g = part ? (ngroups - 1 - p) : p;
        if (part && g <= p) break;          // odd middle group / self-pair

        const int pidx = g * 32 + n;
        const bool live = pidx < nseq;
        const int seq  = live ? perm[pidx] : 0;
        const int len  = live ? l[seq] : 0;

        // trip count = max length over this group's 32 sequences
        int mx = len;
        #pragma unroll
        for (int d = 1; d < 32; d <<= 1) {
            int o = __shfl_xor(mx, d);
            mx = mx > o ? mx : o;
        }
        const int maxlen = mx;

        unsigned int* po = (unsigned int*)emb + (size_t)seq * 16 + 4 * half;
        if (live && len == 0) {             // len==0 -> emb stays zero
            const u32x4 z = {0u, 0u, 0u, 0u};
            *(u32x4*)po       = z;
            *(u32x4*)(po + 8) = z;
        }

        const int base = seq * tmax;
        int off = len - 1;                  // x at step t = hin[len-1-t]
        float x0 = hin[base + (off > 0 ? off : 0)];
        float x1 = hin[base + (off - 1 > 0 ? off - 1 : 0)];

        u32x4 H0 = {0u, 0u, 0u, 0u}, H1 = {0u, 0u, 0u, 0u};
        const int tstore = len - 1;

        for (int t = 0; t < maxlen; ++t) {
            const int off2 = off - 2;
            const float x2 = hin[base + (off2 > 0 ? off2 : 0)];   // prefetch

            const unsigned int xw = pk_f16(x0, 0.0f);
            const f16x8 XB = __builtin_bit_cast(f16x8,
                                 (u32x4){xw, zz[0], zz[1], zz[2]});
            f32x16 acc = MFMA32(XA, XB, bC);
            acc = MFMA32(WA, __builtin_bit_cast(f16x8, H0), acc);
            acc = MFMA32(WB, __builtin_bit_cast(f16x8, H1), acc);

            float hv[16];
            #pragma unroll
            for (int r = 0; r < 16; ++r) hv[r] = pade_tanh(acc[r]);

            unsigned int P0 = pk_f16(hv[0],  hv[1]),  P1 = pk_f16(hv[2],  hv[3]);
            unsigned int P2 = pk_f16(hv[4],  hv[5]),  P3 = pk_f16(hv[6],  hv[7]);
            unsigned int P4 = pk_f16(hv[8],  hv[9]),  P5 = pk_f16(hv[10], hv[11]);
            unsigned int P6 = pk_f16(hv[12], hv[13]), P7 = pk_f16(hv[14], hv[15]);
            pl32swap(P0, P2);
            pl32swap(P1, P3);
            pl32swap(P4, P6);
            pl32swap(P5, P7);

            H0 = (u32x4){P0, P1, P2, P3};
            H1 = (u32x4){P4, P5, P6, P7};

            if (t == tstore) {              // last valid step: emit this seq
                *(u32x4*)po       = H0;
                *(u32x4*)(po + 8) = H1;
            }

            x0 = x1; x1 = x2; --off;
        }
    }
}

// ---- MLP, compile-time-specialized scalar version (round-4: passing, fast) ----
template<int FEATDIM, int ROUT>
__global__ __launch_bounds__(256) void mlp_spec_kernel(
    const _Float16* __restrict__ emb,
    const float* __restrict__ W1, const float* __restrict__ b1,
    const float* __restrict__ W2, const float* __restrict__ b2,
    const float* __restrict__ W3, const float* __restrict__ b3,
    float* __restrict__ out, int n)
{
    __shared__ float sW1[FEATDIM * 32];
    __shared__ float sW2[32 * 32];
    __shared__ float sW3[32 * ROUT];
    __shared__ float sB[64 + ROUT];
    for (int k = threadIdx.x; k < FEATDIM * 32; k += 256) sW1[k] = W1[k];
    for (int k = threadIdx.x; k < 32 * 32;      k += 256) sW2[k] = W2[k];
    if (threadIdx.x < 32 * ROUT) sW3[threadIdx.x] = W3[threadIdx.x];
    if (threadIdx.x < 32)                 sB[threadIdx.x] = b1[threadIdx.x];
    else if (threadIdx.x < 64)            sB[threadIdx.x] = b2[threadIdx.x - 32];
    else if (threadIdx.x < 64 + ROUT)     sB[threadIdx.x] = b3[threadIdx.x - 64];
    __syncthreads();

    const int i = blockIdx.x * 256 + threadIdx.x;
    if (i >= n) return;
    const _Float16* f = emb + (size_t)i * FEATDIM;

    float z1[32];
    #pragma unroll
    for (int c = 0; c < 32; ++c) z1[c] = sB[c];
    #pragma unroll 2
    for (int k = 0; k < FEATDIM; k += 8) {
        const f16x8 fv = *(const f16x8*)(f + k);      // 16B coalesced load
        #pragma unroll
        for (int kk = 0; kk < 8; ++kk) {
            const float xk = (float)fv[kk];
            const float* wr = &sW1[(k + kk) * 32];    // uniform addr: broadcast
            #pragma unroll
            for (int c = 0; c < 32; c += 4) {
                const float4 w = *(const float4*)(wr + c);
                z1[c]     = fmaf(xk, w.x, z1[c]);
                z1[c + 1] = fmaf(xk, w.y, z1[c + 1]);
                z1[c + 2] = fmaf(xk, w.z, z1[c + 2]);
                z1[c + 3] = fmaf(xk, w.w, z1[c + 3]);
            }
        }
    }
    #pragma unroll
    for (int c = 0; c < 32; ++c) z1[c] = fmaxf(z1[c], 0.0f);

    float z2[32];
    #pragma unroll
    for (int c = 0; c < 32; ++c) z2[c] = sB[32 + c];
    #pragma unroll 4
    for (int j = 0; j < 32; ++j) {
        const float zj = z1[j];
        const float* wr = &sW2[j * 32];
        #pragma unroll
        for (int c = 0; c < 32; c += 4) {
            const float4 w = *(const float4*)(wr + c);
            z2[c]     = fmaf(zj, w.x, z2[c]);
            z2[c + 1] = fmaf(zj, w.y, z2[c + 1]);
            z2[c + 2] = fmaf(zj, w.z, z2[c + 2]);
            z2[c + 3] = fmaf(zj, w.w, z2[c + 3]);
        }
    }
    #pragma unroll
    for (int c = 0; c < 32; ++c) z2[c] = fmaxf(z2[c], 0.0f);

    float lo[ROUT];
    #pragma unroll
    for (int c = 0; c < ROUT; ++c) lo[c] = sB[64 + c];
    #pragma unroll
    for (int j = 0; j < 32; ++j) {
        const float zj = z2[j];
        #pragma unroll
        for (int c = 0; c < ROUT; ++c)
            lo[c] = fmaf(zj, sW3[j * ROUT + c], lo[c]);
    }
    if (ROUT == 4) {
        *(float4*)(out + (size_t)i * 4) = make_float4(lo[0], lo[1], lo[2], lo[3]);
    } else {
        #pragma unroll
        for (int c = 0; c < ROUT; ++c) out[(size_t)i * ROUT + c] = lo[c];
    }
}

// ---- generic fallback MLP (off-path for this problem) ----
__global__ __launch_bounds__(64) void mlp_kernel(
    const _Float16* __restrict__ emb,
    const float* __restrict__ W1, const float* __restrict__ b1,
    const float* __restrict__ W2, const float* __restrict__ b2,
    const float* __restrict__ W3, const float* __restrict__ b3,
    float* __restrict__ out, int n, int featdim, int rout)
{
    extern __shared__ float smem[];
    float* sW1 = smem;
    float* sW2 = sW1 + featdim * 32;
    float* sW3 = sW2 + 1024;
    float* sB  = sW3 + 32 * rout;
    for (int k = threadIdx.x; k < featdim * 32; k += blockDim.x) sW1[k] = W1[k];
    for (int k = threadIdx.x; k < 1024;         k += blockDim.x) sW2[k] = W2[k];
    for (int k = threadIdx.x; k < 32 * rout;    k += blockDim.x) sW3[k] = W3[k];
    {
        int t = threadIdx.x;
        if (t < 32) {
            sB[t] = b1[t];
            if (t < rout) sB[64 + t] = b3[t];
        } else if (t < 64) {
            sB[t] = b2[t - 32];
        }
    }
    __syncthreads();

    int i = blockIdx.x * blockDim.x + threadIdx.x;
    if (i >= n) return;
    const _Float16* f = emb + (size_t)i * featdim;

    float z1[32];
    #pragma unroll
    for (int c = 0; c < 32; ++c) z1[c] = sB[c];
    for (int k = 0; k < featdim; k += 8) {
        f16x8 fv = *(const f16x8*)(f + k);
        #pragma unroll
        for (int kk = 0; kk < 8; ++kk) {
            const float xk = (float)fv[kk];
            const float* wr = &sW1[(k + kk) * 32];
            #pragma unroll
            for (int c = 0; c < 32; ++c) z1[c] = fmaf(xk, wr[c], z1[c]);
        }
    }
    #pragma unroll
    for (int c = 0; c < 32; ++c) z1[c] = fmaxf(z1[c], 0.0f);

    float z2[32];
    #pragma unroll
    for (int c = 0; c < 32; ++c) z2[c] = sB[32 + c];
    #pragma unroll
    for (int j = 0; j < 32; ++j) {
        const float zj = z1[j];
        const float* wr = &sW2[j * 32];
        #pragma unroll
        for (int c = 0; c < 32; ++c) z2[c] = fmaf(zj, wr[c], z2[c]);
    }
    #pragma unroll
    for (int c = 0; c < 32; ++c) z2[c] = fmaxf(z2[c], 0.0f);

    for (int c = 0; c < rout; ++c) {
        float lo = sB[64 + c];
        #pragma unroll
        for (int j = 0; j < 32; ++j) lo = fmaf(z2[j], sW3[j * rout + c], lo);
        out[(size_t)i * rout + c] = lo;
    }
}

extern "C" void kernel_launch(void* const* d_in, const int* in_sizes, int n_in,
                              void* d_out, int out_size, void* d_ws, size_t ws_size,
                              hipStream_t stream) {
    const float* h    = (const float*)d_in[0];
    const int*   l    = (const int*)d_in[1];
    const float* W_ih = (const float*)d_in[2];
    const float* W_hh = (const float*)d_in[3];
    const float* b_ih = (const float*)d_in[4];
    const float* b_hh = (const float*)d_in[5];
    const float* W1   = (const float*)d_in[6];
    const float* b1   = (const float*)d_in[7];
    const float* W2   = (const float*)d_in[8];
    const float* b2   = (const float*)d_in[9];
    const float* W3   = (const float*)d_in[10];
    const float* b3   = (const float*)d_in[11];
    float* out = (float*)d_out;

    const int nseq = in_sizes[1];               // N*R = 131072
    const int tmax = in_sizes[0] / nseq;        // 256
    const int rout = in_sizes[10] / 32;         // R = 4
    const int n    = nseq / rout;               // 32768
    const int featdim = rout * HDIM;            // 128

    // workspace layout: emb is f16 (8 MB)
    _Float16* emb = (_Float16*)d_ws;
    int* perm = (int*)((char*)d_ws + (size_t)nseq * HDIM * sizeof(_Float16));
    int* cnt  = perm + nseq;
    int* off  = cnt + NBINS;

    hipMemsetAsync(cnt, 0, NBINS * sizeof(int), stream);
    hist_kernel<<<64, 256, 0, stream>>>(l, cnt, nseq);
    scan_kernel<<<1, NBINS, 0, stream>>>(cnt, off);
    scatter_kernel<<<64, 256, 0, stream>>>(l, off, perm, nseq);

    // reflected-pair schedule: wave w handles group w (long) then
    // group ngroups-1-w (short) -> every wave ~equal total steps.
    const int ngroups = (nseq + 31) / 32;
    const int npairs  = (ngroups + 1) / 2;
    const int nblk    = (npairs + 1) / 2;       // 2 waves per block
    rnn_kernel<<<nblk, 128, 0, stream>>>(
        h, l, perm, W_ih, W_hh, b_ih, b_hh, emb, nseq, tmax);

    if (featdim == 128 && rout == 4) {
        mlp_spec_kernel<128, 4><<<(n + 255) / 256, 256, 0, stream>>>(
            emb, W1, b1, W2, b2, W3, b3, out, n);
    } else {
        const int smem_bytes =
            (featdim * 32 + 1024 + 32 * rout + 64 + 32) * sizeof(float);
        mlp_kernel<<<(n + 63) / 64, 64, smem_bytes, stream>>>(
            emb, W1, b1, W2, b2, W3, b3, out, n, featdim, rout);
    }
}

// Round 6
// 387.398 us; speedup vs baseline: 1.0476x; 1.0476x over previous
//
#include <hip/hip_runtime.h>

#define HDIM 32
#define NBINS 512   // lengths occupy bins 0..256; padded to pow2 for the scan

typedef _Float16 f16x8 __attribute__((ext_vector_type(8)));
typedef float f32x16 __attribute__((ext_vector_type(16)));
typedef unsigned int u32x4 __attribute__((ext_vector_type(4)));
#define MFMA32(A,B,C) __builtin_amdgcn_mfma_f32_32x32x16_f16((A),(B),(C),0,0,0)

// pack two f32 -> one u32 of 2 f16 (v_cvt_pkrtz_f16_f32, single VALU op)
__device__ __forceinline__ unsigned int pk_f16(float a, float b) {
    return __builtin_bit_cast(unsigned int, __builtin_amdgcn_cvt_pkrtz(a, b));
}

// sigma: swap bits 2 and 3 of a 5-bit row index. Applying sigma to all
// row-indexed invariants (W_hh rows, W_ih, bias) makes each lane's MFMA
// D registers hold EXACTLY the h-values its own B-fragment needs:
//   half0 D regs r=0..15 -> h{0..7,16..23} = its B k{0..7,16..23}
//   half1 D regs r=0..15 -> h{8..15,24..31} = its B k{8..15,24..31}
// (index-verified against the in-session-verified 32x32x16 mappings)
// => D->B relayout is 8 packs, ZERO cross-lane ops, and the emb store
// layout is unchanged.
__device__ __forceinline__ int sig_row(int m) {
    return (m & ~12) | ((m & 4) << 1) | ((m & 8) >> 1);
}

#define PIN16(a) asm("" : "+v"(a[0]),"+v"(a[1]),"+v"(a[2]),"+v"(a[3]), \
                         "+v"(a[4]),"+v"(a[5]),"+v"(a[6]),"+v"(a[7]), \
                         "+v"(a[8]),"+v"(a[9]),"+v"(a[10]),"+v"(a[11]), \
                         "+v"(a[12]),"+v"(a[13]),"+v"(a[14]),"+v"(a[15]))
#define PIN8(a)  asm("" : "+v"(a[0]),"+v"(a[1]),"+v"(a[2]),"+v"(a[3]), \
                         "+v"(a[4]),"+v"(a[5]),"+v"(a[6]),"+v"(a[7]))

// ---- length-bucketing: counting sort into a permutation (DESCENDING) ----
__global__ __launch_bounds__(256) void hist_kernel(
    const int* __restrict__ l, int* __restrict__ cnt, int nseq)
{
    __shared__ int hc[NBINS];
    for (int k = threadIdx.x; k < NBINS; k += blockDim.x) hc[k] = 0;
    __syncthreads();
    for (int i = blockIdx.x * blockDim.x + threadIdx.x; i < nseq;
         i += gridDim.x * blockDim.x)
        atomicAdd(&hc[l[i]], 1);
    __syncthreads();
    for (int k = threadIdx.x; k < NBINS; k += blockDim.x)
        if (hc[k]) atomicAdd(&cnt[k], hc[k]);
}

// off[t] = sum_{k>t} cnt[k]  (exclusive SUFFIX sum -> longest lengths first)
__global__ __launch_bounds__(NBINS) void scan_kernel(
    const int* __restrict__ cnt, int* __restrict__ off)
{
    __shared__ int sc[NBINS];
    int t = threadIdx.x;
    int v0 = cnt[t];
    sc[t] = v0;
    __syncthreads();
    for (int d = 1; d < NBINS; d <<= 1) {
        int v = (t + d < NBINS) ? sc[t + d] : 0;
        __syncthreads();
        sc[t] += v;
        __syncthreads();
    }
    off[t] = sc[t] - v0;          // strictly-greater suffix sum
}

// Block-aggregated scatter: LDS histogram per block, ONE global atomic per
// touched bin to reserve a range, then LDS cursors for local ranks.
__global__ __launch_bounds__(256) void scatter_kernel(
    const int* __restrict__ l, int* __restrict__ off,
    int* __restrict__ perm, int nseq)
{
    __shared__ int lcur[NBINS];
    const int chunk = (nseq + gridDim.x - 1) / gridDim.x;
    const int lo = blockIdx.x * chunk;
    const int hi = min(nseq, lo + chunk);
    for (int k = threadIdx.x; k < NBINS; k += blockDim.x) lcur[k] = 0;
    __syncthreads();
    for (int i = lo + threadIdx.x; i < hi; i += blockDim.x)
        atomicAdd(&lcur[l[i]], 1);
    __syncthreads();
    for (int k = threadIdx.x; k < NBINS; k += blockDim.x) {
        int c = lcur[k];
        lcur[k] = c ? atomicAdd(&off[k], c) : 0;   // global base for this block
    }
    __syncthreads();
    for (int i = lo + threadIdx.x; i < hi; i += blockDim.x) {
        int p = atomicAdd(&lcur[l[i]], 1);         // LDS cursor = base + rank
        perm[p] = i;
    }
}

// ---- RNN: wave = TWO independent 32-seq groups, MFMA 32x32x16 f16 ----
// Round-6 structure (post-mortem of the round-5 regression):
//  * REVERT to round-4 numerics: exp2-tanh with 2*log2(e) folded into the
//    weights (round-5's pade_tanh measured MORE VALU issue, not less).
//  * 2 CHAINS PER WAVE: round-5 halved wave count with SEQUENTIAL pairing
//    -> 2 waves/SIMD with one serial chain each -> latency-bound (occ 18%,
//    220us). Now the two groups run SIMULTANEOUSLY: 2048 waves x 2
//    independent MFMA/tanh chains = 4 chains/SIMD (round-4's effective
//    parallelism) + perfect balance (adjacent sorted groups) + halved
//    loop overhead.
//  * SIGMA ROW PERMUTATION (see sig_row): relayout = 8 packs, no permlane.
__global__ __launch_bounds__(64, 2) void rnn_kernel(
    const float* __restrict__ hin, const int* __restrict__ l,
    const int* __restrict__ perm,
    const float* __restrict__ W_ih, const float* __restrict__ W_hh,
    const float* __restrict__ b_ih, const float* __restrict__ b_hh,
    _Float16* __restrict__ emb, int nseq, int tmax)
{
    const int lane = threadIdx.x & 63;
    const int n    = lane & 31;
    const int half = lane >> 5;
    const int ngroups = (nseq + 31) >> 5;
    const int gA = blockIdx.x * 2;
    const int gB = gA + 1;

    const float S = 2.8853900817779268f;   // 2*log2(e), folded into weights
    const int sn = sig_row(n);

    // persistent A fragments (W_hh rows sigma-permuted, *S, f16), pinned
    unsigned int qw[8];
    {
        f16x8 w[2];
        #pragma unroll
        for (int f = 0; f < 2; ++f)
            #pragma unroll
            for (int j = 0; j < 8; ++j)
                w[f][j] = (_Float16)(W_hh[sn * 32 + 16 * f + 8 * half + j] * S);
        u32x4 qa = __builtin_bit_cast(u32x4, w[0]);
        u32x4 qb = __builtin_bit_cast(u32x4, w[1]);
        #pragma unroll
        for (int c = 0; c < 4; ++c) { qw[c] = qa[c]; qw[4 + c] = qb[c]; }
    }
    PIN8(qw);
    const f16x8 WA = __builtin_bit_cast(f16x8, (u32x4){qw[0], qw[1], qw[2], qw[3]});
    const f16x8 WB = __builtin_bit_cast(f16x8, (u32x4){qw[4], qw[5], qw[6], qw[7]});

    // input-path MFMA A-fragment: A[m][0] = W_ih[sig(m)]*S on half0, else 0
    unsigned int xaw = half ? 0u : pk_f16(W_ih[sn] * S, 0.0f);
    unsigned int zz[3] = {0u, 0u, 0u};
    asm("" : "+v"(xaw), "+v"(zz[0]), "+v"(zz[1]), "+v"(zz[2]));
    const f16x8 XA = __builtin_bit_cast(f16x8, (u32x4){xaw, zz[0], zz[1], zz[2]});

    // bias (sigma-permuted rows, *S) as the f32 MFMA C operand
    float bv[16];
    #pragma unroll
    for (int r = 0; r < 16; ++r) {
        const int g = sig_row((r & 3) + 8 * (r >> 2) + 4 * half);
        bv[r] = (b_ih[g] + b_hh[g]) * S;
    }
    PIN16(bv);
    f32x16 bC;
    #pragma unroll
    for (int r = 0; r < 16; ++r) bC[r] = bv[r];

    // ---- chain setups ----
    const int pidxA = gA * 32 + n;
    const bool liveA = pidxA < nseq;
    const int seqA = liveA ? perm[pidxA] : 0;
    const int lenA = liveA ? l[seqA] : 0;

    const int pidxB = gB * 32 + n;
    const bool liveB = (gB < ngroups) && (pidxB < nseq);
    const int seqB = liveB ? perm[pidxB] : 0;
    const int lenB = liveB ? l[seqB] : 0;

    // trip count = max length over both chains (adjacent sorted groups)
    int mx = lenA > lenB ? lenA : lenB;
    #pragma unroll
    for (int d = 1; d < 32; d <<= 1) {
        int o = __shfl_xor(mx, d);
        mx = mx > o ? mx : o;
    }
    const int maxlen = mx;

    unsigned int* poA = (unsigned int*)emb + (size_t)seqA * 16 + 4 * half;
    unsigned int* poB = (unsigned int*)emb + (size_t)seqB * 16 + 4 * half;
    {
        const u32x4 z = {0u, 0u, 0u, 0u};
        if (liveA && lenA == 0) { *(u32x4*)poA = z; *(u32x4*)(poA + 8) = z; }
        if (liveB && lenB == 0) { *(u32x4*)poB = z; *(u32x4*)(poB + 8) = z; }
    }

    const int baseA = seqA * tmax, baseB = seqB * tmax;
    int offA = lenA - 1, offB = lenB - 1;
    float x0A = hin[baseA + (offA > 0 ? offA : 0)];
    float x1A = hin[baseA + (offA - 1 > 0 ? offA - 1 : 0)];
    float x0B = hin[baseB + (offB > 0 ? offB : 0)];
    float x1B = hin[baseB + (offB - 1 > 0 ? offB - 1 : 0)];

    u32x4 H0A = {0u,0u,0u,0u}, H1A = {0u,0u,0u,0u};
    u32x4 H0B = {0u,0u,0u,0u}, H1B = {0u,0u,0u,0u};
    const int tsA = lenA - 1, tsB = lenB - 1;

    for (int t = 0; t < maxlen; ++t) {
        const int o2A = offA - 2, o2B = offB - 2;
        const float x2A = hin[baseA + (o2A > 0 ? o2A : 0)];   // prefetch
        const float x2B = hin[baseB + (o2B > 0 ? o2B : 0)];

        // chain A: acc = x*W_ih + b (via matrix pipe) + W_hh*h
        const f16x8 XBA = __builtin_bit_cast(f16x8,
                              (u32x4){pk_f16(x0A, 0.0f), zz[0], zz[1], zz[2]});
        f32x16 accA = MFMA32(XA, XBA, bC);
        accA = MFMA32(WA, __builtin_bit_cast(f16x8, H0A), accA);
        accA = MFMA32(WB, __builtin_bit_cast(f16x8, H1A), accA);

        // chain B (independent -> scheduler interleaves with A's latency)
        const f16x8 XBB = __builtin_bit_cast(f16x8,
                              (u32x4){pk_f16(x0B, 0.0f), zz[0], zz[1], zz[2]});
        f32x16 accB = MFMA32(XA, XBB, bC);
        accB = MFMA32(WA, __builtin_bit_cast(f16x8, H0B), accB);
        accB = MFMA32(WB, __builtin_bit_cast(f16x8, H1B), accB);

        // tanh(z), acc = 2*log2(e)*z :  1 - 2/(exp2(acc)+1)
        float hvA[16], hvB[16];
        #pragma unroll
        for (int r = 0; r < 16; ++r) {
            const float eA = __builtin_amdgcn_exp2f(accA[r]);
            hvA[r] = fmaf(-2.0f, __builtin_amdgcn_rcpf(eA + 1.0f), 1.0f);
            const float eB = __builtin_amdgcn_exp2f(accB[r]);
            hvB[r] = fmaf(-2.0f, __builtin_amdgcn_rcpf(eB + 1.0f), 1.0f);
        }

        // sigma layout: D regs pack DIRECTLY into B-fragments (no permlane)
        H0A = (u32x4){pk_f16(hvA[0],hvA[1]),  pk_f16(hvA[2],hvA[3]),
                      pk_f16(hvA[4],hvA[5]),  pk_f16(hvA[6],hvA[7])};
        H1A = (u32x4){pk_f16(hvA[8],hvA[9]),  pk_f16(hvA[10],hvA[11]),
                      pk_f16(hvA[12],hvA[13]),pk_f16(hvA[14],hvA[15])};
        H0B = (u32x4){pk_f16(hvB[0],hvB[1]),  pk_f16(hvB[2],hvB[3]),
                      pk_f16(hvB[4],hvB[5]),  pk_f16(hvB[6],hvB[7])};
        H1B = (u32x4){pk_f16(hvB[8],hvB[9]),  pk_f16(hvB[10],hvB[11]),
                      pk_f16(hvB[12],hvB[13]),pk_f16(hvB[14],hvB[15])};

        if (t == tsA) { *(u32x4*)poA = H0A; *(u32x4*)(poA + 8) = H1A; }
        if (t == tsB) { *(u32x4*)poB = H0B; *(u32x4*)(poB + 8) = H1B; }

        x0A = x1A; x1A = x2A; --offA;
        x0B = x1B; x1B = x2B; --offB;
    }
}

// ---- MLP, compile-time-specialized scalar version (round-4: passing, fast) ----
template<int FEATDIM, int ROUT>
__global__ __launch_bounds__(256) void mlp_spec_kernel(
    const _Float16* __restrict__ emb,
    const float* __restrict__ W1, const float* __restrict__ b1,
    const float* __restrict__ W2, const float* __restrict__ b2,
    const float* __restrict__ W3, const float* __restrict__ b3,
    float* __restrict__ out, int n)
{
    __shared__ float sW1[FEATDIM * 32];
    __shared__ float sW2[32 * 32];
    __shared__ float sW3[32 * ROUT];
    __shared__ float sB[64 + ROUT];
    for (int k = threadIdx.x; k < FEATDIM * 32; k += 256) sW1[k] = W1[k];
    for (int k = threadIdx.x; k < 32 * 32;      k += 256) sW2[k] = W2[k];
    if (threadIdx.x < 32 * ROUT) sW3[threadIdx.x] = W3[threadIdx.x];
    if (threadIdx.x < 32)                 sB[threadIdx.x] = b1[threadIdx.x];
    else if (threadIdx.x < 64)            sB[threadIdx.x] = b2[threadIdx.x - 32];
    else if (threadIdx.x < 64 + ROUT)     sB[threadIdx.x] = b3[threadIdx.x - 64];
    __syncthreads();

    const int i = blockIdx.x * 256 + threadIdx.x;
    if (i >= n) return;
    const _Float16* f = emb + (size_t)i * FEATDIM;

    float z1[32];
    #pragma unroll
    for (int c = 0; c < 32; ++c) z1[c] = sB[c];
    #pragma unroll 2
    for (int k = 0; k < FEATDIM; k += 8) {
        const f16x8 fv = *(const f16x8*)(f + k);      // 16B coalesced load
        #pragma unroll
        for (int kk = 0; kk < 8; ++kk) {
            const float xk = (float)fv[kk];
            const float* wr = &sW1[(k + kk) * 32];    // uniform addr: broadcast
            #pragma unroll
            for (int c = 0; c < 32; c += 4) {
                const float4 w = *(const float4*)(wr + c);
                z1[c]     = fmaf(xk, w.x, z1[c]);
                z1[c + 1] = fmaf(xk, w.y, z1[c + 1]);
                z1[c + 2] = fmaf(xk, w.z, z1[c + 2]);
                z1[c + 3] = fmaf(xk, w.w, z1[c + 3]);
            }
        }
    }
    #pragma unroll
    for (int c = 0; c < 32; ++c) z1[c] = fmaxf(z1[c], 0.0f);

    float z2[32];
    #pragma unroll
    for (int c = 0; c < 32; ++c) z2[c] = sB[32 + c];
    #pragma unroll 4
    for (int j = 0; j < 32; ++j) {
        const float zj = z1[j];
        const float* wr = &sW2[j * 32];
        #pragma unroll
        for (int c = 0; c < 32; c += 4) {
            const float4 w = *(const float4*)(wr + c);
            z2[c]     = fmaf(zj, w.x, z2[c]);
            z2[c + 1] = fmaf(zj, w.y, z2[c + 1]);
            z2[c + 2] = fmaf(zj, w.z, z2[c + 2]);
            z2[c + 3] = fmaf(zj, w.w, z2[c + 3]);
        }
    }
    #pragma unroll
    for (int c = 0; c < 32; ++c) z2[c] = fmaxf(z2[c], 0.0f);

    float lo[ROUT];
    #pragma unroll
    for (int c = 0; c < ROUT; ++c) lo[c] = sB[64 + c];
    #pragma unroll
    for (int j = 0; j < 32; ++j) {
        const float zj = z2[j];
        #pragma unroll
        for (int c = 0; c < ROUT; ++c)
            lo[c] = fmaf(zj, sW3[j * ROUT + c], lo[c]);
    }
    if (ROUT == 4) {
        *(float4*)(out + (size_t)i * 4) = make_float4(lo[0], lo[1], lo[2], lo[3]);
    } else {
        #pragma unroll
        for (int c = 0; c < ROUT; ++c) out[(size_t)i * ROUT + c] = lo[c];
    }
}

// ---- generic fallback MLP (off-path for this problem) ----
__global__ __launch_bounds__(64) void mlp_kernel(
    const _Float16* __restrict__ emb,
    const float* __restrict__ W1, const float* __restrict__ b1,
    const float* __restrict__ W2, const float* __restrict__ b2,
    const float* __restrict__ W3, const float* __restrict__ b3,
    float* __restrict__ out, int n, int featdim, int rout)
{
    extern __shared__ float smem[];
    float* sW1 = smem;
    float* sW2 = sW1 + featdim * 32;
    float* sW3 = sW2 + 1024;
    float* sB  = sW3 + 32 * rout;
    for (int k = threadIdx.x; k < featdim * 32; k += blockDim.x) sW1[k] = W1[k];
    for (int k = threadIdx.x; k < 1024;         k += blockDim.x) sW2[k] = W2[k];
    for (int k = threadIdx.x; k < 32 * rout;    k += blockDim.x) sW3[k] = W3[k];
    {
        int t = threadIdx.x;
        if (t < 32) {
            sB[t] = b1[t];
            if (t < rout) sB[64 + t] = b3[t];
        } else if (t < 64) {
            sB[t] = b2[t - 32];
        }
    }
    __syncthreads();

    int i = blockIdx.x * blockDim.x + threadIdx.x;
    if (i >= n) return;
    const _Float16* f = emb + (size_t)i * featdim;

    float z1[32];
    #pragma unroll
    for (int c = 0; c < 32; ++c) z1[c] = sB[c];
    for (int k = 0; k < featdim; k += 8) {
        f16x8 fv = *(const f16x8*)(f + k);
        #pragma unroll
        for (int kk = 0; kk < 8; ++kk) {
            const float xk = (float)fv[kk];
            const float* wr = &sW1[(k + kk) * 32];
            #pragma unroll
            for (int c = 0; c < 32; ++c) z1[c] = fmaf(xk, wr[c], z1[c]);
        }
    }
    #pragma unroll
    for (int c = 0; c < 32; ++c) z1[c] = fmaxf(z1[c], 0.0f);

    float z2[32];
    #pragma unroll
    for (int c = 0; c < 32; ++c) z2[c] = sB[32 + c];
    #pragma unroll
    for (int j = 0; j < 32; ++j) {
        const float zj = z1[j];
        const float* wr = &sW2[j * 32];
        #pragma unroll
        for (int c = 0; c < 32; ++c) z2[c] = fmaf(zj, wr[c], z2[c]);
    }
    #pragma unroll
    for (int c = 0; c < 32; ++c) z2[c] = fmaxf(z2[c], 0.0f);

    for (int c = 0; c < rout; ++c) {
        float lo = sB[64 + c];
        #pragma unroll
        for (int j = 0; j < 32; ++j) lo = fmaf(z2[j], sW3[j * rout + c], lo);
        out[(size_t)i * rout + c] = lo;
    }
}

extern "C" void kernel_launch(void* const* d_in, const int* in_sizes, int n_in,
                              void* d_out, int out_size, void* d_ws, size_t ws_size,
                              hipStream_t stream) {
    const float* h    = (const float*)d_in[0];
    const int*   l    = (const int*)d_in[1];
    const float* W_ih = (const float*)d_in[2];
    const float* W_hh = (const float*)d_in[3];
    const float* b_ih = (const float*)d_in[4];
    const float* b_hh = (const float*)d_in[5];
    const float* W1   = (const float*)d_in[6];
    const float* b1   = (const float*)d_in[7];
    const float* W2   = (const float*)d_in[8];
    const float* b2   = (const float*)d_in[9];
    const float* W3   = (const float*)d_in[10];
    const float* b3   = (const float*)d_in[11];
    float* out = (float*)d_out;

    const int nseq = in_sizes[1];               // N*R = 131072
    const int tmax = in_sizes[0] / nseq;        // 256
    const int rout = in_sizes[10] / 32;         // R = 4
    const int n    = nseq / rout;               // 32768
    const int featdim = rout * HDIM;            // 128

    // workspace layout: emb is f16 (8 MB)
    _Float16* emb = (_Float16*)d_ws;
    int* perm = (int*)((char*)d_ws + (size_t)nseq * HDIM * sizeof(_Float16));
    int* cnt  = perm + nseq;
    int* off  = cnt + NBINS;

    hipMemsetAsync(cnt, 0, NBINS * sizeof(int), stream);
    hist_kernel<<<64, 256, 0, stream>>>(l, cnt, nseq);
    scan_kernel<<<1, NBINS, 0, stream>>>(cnt, off);
    scatter_kernel<<<64, 256, 0, stream>>>(l, off, perm, nseq);

    // 2 adjacent sorted groups per wave (simultaneous chains), 1 wave/block,
    // longest pairs dispatched first
    const int ngroups = (nseq + 31) / 32;
    const int nblk    = (ngroups + 1) / 2;
    rnn_kernel<<<nblk, 64, 0, stream>>>(
        h, l, perm, W_ih, W_hh, b_ih, b_hh, emb, nseq, tmax);

    if (featdim == 128 && rout == 4) {
        mlp_spec_kernel<128, 4><<<(n + 255) / 256, 256, 0, stream>>>(
            emb, W1, b1, W2, b2, W3, b3, out, n);
    } else {
        const int smem_bytes =
            (featdim * 32 + 1024 + 32 * rout + 64 + 32) * sizeof(float);
        mlp_kernel<<<(n + 63) / 64, 64, smem_bytes, stream>>>(
            emb, W1, b1, W2, b2, W3, b3, out, n, featdim, rout);
    }
}

// Round 7
// 362.152 us; speedup vs baseline: 1.1206x; 1.0697x over previous
//
#include <hip/hip_runtime.h>

#define HDIM 32
#define NBINS 512   // lengths occupy bins 0..256; padded to pow2 for the scan

typedef _Float16 f16x8 __attribute__((ext_vector_type(8)));
typedef float f32x4 __attribute__((ext_vector_type(4)));
typedef unsigned int u32x4 __attribute__((ext_vector_type(4)));
#define MFMA16(A,B,C) __builtin_amdgcn_mfma_f32_16x16x32_f16((A),(B),(C),0,0,0)

// pack two f32 -> one u32 of 2 f16 (v_cvt_pkrtz_f16_f32, single VALU op)
__device__ __forceinline__ unsigned int pk_f16(float a, float b) {
    return __builtin_bit_cast(unsigned int, __builtin_amdgcn_cvt_pkrtz(a, b));
}

#define PIN8(a)  asm("" : "+v"(a[0]),"+v"(a[1]),"+v"(a[2]),"+v"(a[3]), \
                         "+v"(a[4]),"+v"(a[5]),"+v"(a[6]),"+v"(a[7]))
#define PIN4(a)  asm("" : "+v"(a[0]),"+v"(a[1]),"+v"(a[2]),"+v"(a[3]))

// ---- length-bucketing: counting sort into a permutation (DESCENDING) ----
__global__ __launch_bounds__(256) void hist_kernel(
    const int* __restrict__ l, int* __restrict__ cnt, int nseq)
{
    __shared__ int hc[NBINS];
    for (int k = threadIdx.x; k < NBINS; k += blockDim.x) hc[k] = 0;
    __syncthreads();
    for (int i = blockIdx.x * blockDim.x + threadIdx.x; i < nseq;
         i += gridDim.x * blockDim.x)
        atomicAdd(&hc[l[i]], 1);
    __syncthreads();
    for (int k = threadIdx.x; k < NBINS; k += blockDim.x)
        if (hc[k]) atomicAdd(&cnt[k], hc[k]);
}

// off[t] = sum_{k>t} cnt[k]  (exclusive SUFFIX sum -> longest lengths first)
__global__ __launch_bounds__(NBINS) void scan_kernel(
    const int* __restrict__ cnt, int* __restrict__ off)
{
    __shared__ int sc[NBINS];
    int t = threadIdx.x;
    int v0 = cnt[t];
    sc[t] = v0;
    __syncthreads();
    for (int d = 1; d < NBINS; d <<= 1) {
        int v = (t + d < NBINS) ? sc[t + d] : 0;
        __syncthreads();
        sc[t] += v;
        __syncthreads();
    }
    off[t] = sc[t] - v0;          // strictly-greater suffix sum
}

// Block-aggregated scatter: LDS histogram per block, ONE global atomic per
// touched bin to reserve a range, then LDS cursors for local ranks.
__global__ __launch_bounds__(256) void scatter_kernel(
    const int* __restrict__ l, int* __restrict__ off,
    int* __restrict__ perm, int nseq)
{
    __shared__ int lcur[NBINS];
    const int chunk = (nseq + gridDim.x - 1) / gridDim.x;
    const int lo = blockIdx.x * chunk;
    const int hi = min(nseq, lo + chunk);
    for (int k = threadIdx.x; k < NBINS; k += blockDim.x) lcur[k] = 0;
    __syncthreads();
    for (int i = lo + threadIdx.x; i < hi; i += blockDim.x)
        atomicAdd(&lcur[l[i]], 1);
    __syncthreads();
    for (int k = threadIdx.x; k < NBINS; k += blockDim.x) {
        int c = lcur[k];
        lcur[k] = c ? atomicAdd(&off[k], c) : 0;   // global base for this block
    }
    __syncthreads();
    for (int i = lo + threadIdx.x; i < hi; i += blockDim.x) {
        int p = atomicAdd(&lcur[l[i]], 1);         // LDS cursor = base + rank
        perm[p] = i;
    }
}

// ---- RNN: wave = 16 (length-matched) sequences, MFMA 16x16x32 f16 ----
// Round-7: the r4/r5/r6 schedule experiments pinned the bottleneck as the
// TRANSCENDENTAL pipe (~16 cyc/wave64 trans op; floor ~109us at 100% util).
// r4 (32-seq groups) capped at 4096 waves = 4/SIMD = 65% trans util. This
// round: 16-seq groups -> 8192 waves = 8/SIMD = 32 waves/CU (hardware max).
//
// 16x16x32 fragment mappings (C/D is guide-verified m89; A/B by the same
// lane->k pattern as the in-session-verified 32x32x16 shape):
//   A[m][k]: m = lane&15, k = 8*(lane>>4) + j   (j = 0..7)
//   B[k][n]: n = lane&15, k = 8*(lane>>4) + j
//   C/D:     col n = lane&15, row m = 4*(lane>>4) + r  (r = 0..3)
// Lane roles: s = lane&15 is BOTH this lane's A-row index and its seq
// (B-col); q = lane>>4 is its k-quarter / D-row block.
//
// SIGMA ROW PERMUTATION (r6-verified technique, re-derived for 16x16):
// tile0 rows sig0(m)=8*(m>>2)+(m&3), tile1 rows sig1(m)=sig0(m)+4. Then
// lane (s,q)'s D regs are exactly its B k-slots:
//   acc0[r] -> row sig0(4q+r) = 8q+r,  acc1[r] -> sig1(4q+r) = 8q+4+r
//   => B elems j=0..7 (k=8q+j) = {tanh(acc0[0..3]), tanh(acc1[0..3])}
// Zero cross-lane relayout; emb store layout unchanged (lane owns row
// u32s [4q..4q+3] = h[8q..8q+7]).
// Input path: acc init = fmaf(x_s, W_ih[8q+rr], b[8q+rr]) (8 FMAs; exact
// f32 bias path). exp2-tanh with S=2*log2(e) folded into W_hh/W_ih/b.
__global__ __launch_bounds__(64, 8) void rnn_kernel(
    const float* __restrict__ hin, const int* __restrict__ l,
    const int* __restrict__ perm,
    const float* __restrict__ W_ih, const float* __restrict__ W_hh,
    const float* __restrict__ b_ih, const float* __restrict__ b_hh,
    _Float16* __restrict__ emb, int nseq, int tmax)
{
    const int lane = threadIdx.x & 63;
    const int s    = lane & 15;          // seq within group; also A-row index
    const int q    = lane >> 4;          // k-quarter / D-row block

    const int pidx = blockIdx.x * 16 + s;
    const bool live = pidx < nseq;
    const int seq  = live ? perm[pidx] : 0;
    const int len  = live ? l[seq] : 0;

    const float S = 2.8853900817779268f;   // 2*log2(e), folded into weights

    // A fragments: tile0 = W_hh[sig0(m)][k]*S, tile1 = W_hh[sig0(m)+4][k]*S
    const int s0 = 8 * (s >> 2) + (s & 3);     // sig0(m) for m = s
    unsigned int q0[4], q1[4];
    {
        f16x8 w0, w1;
        #pragma unroll
        for (int j = 0; j < 8; ++j) {
            w0[j] = (_Float16)(W_hh[s0 * 32 + 8 * q + j] * S);
            w1[j] = (_Float16)(W_hh[(s0 + 4) * 32 + 8 * q + j] * S);
        }
        u32x4 a = __builtin_bit_cast(u32x4, w0);
        u32x4 b = __builtin_bit_cast(u32x4, w1);
        #pragma unroll
        for (int c = 0; c < 4; ++c) { q0[c] = a[c]; q1[c] = b[c]; }
    }
    PIN4(q0);
    PIN4(q1);
    const f16x8 A0 = __builtin_bit_cast(f16x8, (u32x4){q0[0], q0[1], q0[2], q0[3]});
    const f16x8 A1 = __builtin_bit_cast(f16x8, (u32x4){q1[0], q1[1], q1[2], q1[3]});

    // C-init constants: rows 8q+rr (rr=0..7); wv/bv scaled by S, pinned
    float wv[8], bv[8];
    #pragma unroll
    for (int rr = 0; rr < 8; ++rr) {
        const int row = 8 * q + rr;
        wv[rr] = W_ih[row] * S;
        bv[rr] = (b_ih[row] + b_hh[row]) * S;
    }
    PIN8(wv);
    PIN8(bv);

    // trip count = max length over the group's 16 seqs (replicas share len)
    int mx = len;
    #pragma unroll
    for (int d = 1; d < 64; d <<= 1) {
        int o = __shfl_xor(mx, d);
        mx = mx > o ? mx : o;
    }
    const int maxlen = mx;

    // this lane owns emb row u32s [4q .. 4q+3] = h[8q .. 8q+7]
    unsigned int* po = (unsigned int*)emb + (size_t)seq * 16 + 4 * q;
    if (live && len == 0) {                 // len==0 -> emb stays zero
        *(u32x4*)po = (u32x4){0u, 0u, 0u, 0u};
    }

    const int base = seq * tmax;
    int off = len - 1;                      // x at step t = hin[len-1-t]
    float x0 = hin[base + (off > 0 ? off : 0)];
    float x1 = hin[base + (off - 1 > 0 ? off - 1 : 0)];

    u32x4 H = {0u, 0u, 0u, 0u};             // h, f16, B-fragment layout
    const int tstore = len - 1;

    for (int t = 0; t < maxlen; ++t) {
        const int off2 = off - 2;
        const float x2 = hin[base + (off2 > 0 ? off2 : 0)];   // prefetch

        f32x4 acc0, acc1;
        #pragma unroll
        for (int r = 0; r < 4; ++r) {
            acc0[r] = fmaf(x0, wv[r],     bv[r]);       // row 8q+r
            acc1[r] = fmaf(x0, wv[4 + r], bv[4 + r]);   // row 8q+4+r
        }
        const f16x8 Hf = __builtin_bit_cast(f16x8, H);
        acc0 = MFMA16(A0, Hf, acc0);
        acc1 = MFMA16(A1, Hf, acc1);

        // tanh(z), acc = 2*log2(e)*z :  1 - 2/(exp2(acc)+1)
        float hv[8];
        #pragma unroll
        for (int r = 0; r < 4; ++r) {
            const float e0 = __builtin_amdgcn_exp2f(acc0[r]);
            hv[r]     = fmaf(-2.0f, __builtin_amdgcn_rcpf(e0 + 1.0f), 1.0f);
            const float e1 = __builtin_amdgcn_exp2f(acc1[r]);
            hv[4 + r] = fmaf(-2.0f, __builtin_amdgcn_rcpf(e1 + 1.0f), 1.0f);
        }

        // sigma layout: D regs pack DIRECTLY into the B-fragment (k=8q+j)
        H = (u32x4){pk_f16(hv[0], hv[1]), pk_f16(hv[2], hv[3]),
                    pk_f16(hv[4], hv[5]), pk_f16(hv[6], hv[7])};

        if (t == tstore) *(u32x4*)po = H;   // last valid step: emit this seq

        x0 = x1; x1 = x2; --off;
    }
}

// ---- MLP, compile-time-specialized scalar version (round-4: passing, fast) ----
template<int FEATDIM, int ROUT>
__global__ __launch_bounds__(256) void mlp_spec_kernel(
    const _Float16* __restrict__ emb,
    const float* __restrict__ W1, const float* __restrict__ b1,
    const float* __restrict__ W2, const float* __restrict__ b2,
    const float* __restrict__ W3, const float* __restrict__ b3,
    float* __restrict__ out, int n)
{
    typedef _Float16 lf16x8 __attribute__((ext_vector_type(8)));
    __shared__ float sW1[FEATDIM * 32];
    __shared__ float sW2[32 * 32];
    __shared__ float sW3[32 * ROUT];
    __shared__ float sB[64 + ROUT];
    for (int k = threadIdx.x; k < FEATDIM * 32; k += 256) sW1[k] = W1[k];
    for (int k = threadIdx.x; k < 32 * 32;      k += 256) sW2[k] = W2[k];
    if (threadIdx.x < 32 * ROUT) sW3[threadIdx.x] = W3[threadIdx.x];
    if (threadIdx.x < 32)                 sB[threadIdx.x] = b1[threadIdx.x];
    else if (threadIdx.x < 64)            sB[threadIdx.x] = b2[threadIdx.x - 32];
    else if (threadIdx.x < 64 + ROUT)     sB[threadIdx.x] = b3[threadIdx.x - 64];
    __syncthreads();

    const int i = blockIdx.x * 256 + threadIdx.x;
    if (i >= n) return;
    const _Float16* f = emb + (size_t)i * FEATDIM;

    float z1[32];
    #pragma unroll
    for (int c = 0; c < 32; ++c) z1[c] = sB[c];
    #pragma unroll 2
    for (int k = 0; k < FEATDIM; k += 8) {
        const lf16x8 fv = *(const lf16x8*)(f + k);    // 16B coalesced load
        #pragma unroll
        for (int kk = 0; kk < 8; ++kk) {
            const float xk = (float)fv[kk];
            const float* wr = &sW1[(k + kk) * 32];    // uniform addr: broadcast
            #pragma unroll
            for (int c = 0; c < 32; c += 4) {
                const float4 w = *(const float4*)(wr + c);
                z1[c]     = fmaf(xk, w.x, z1[c]);
                z1[c + 1] = fmaf(xk, w.y, z1[c + 1]);
                z1[c + 2] = fmaf(xk, w.z, z1[c + 2]);
                z1[c + 3] = fmaf(xk, w.w, z1[c + 3]);
            }
        }
    }
    #pragma unroll
    for (int c = 0; c < 32; ++c) z1[c] = fmaxf(z1[c], 0.0f);

    float z2[32];
    #pragma unroll
    for (int c = 0; c < 32; ++c) z2[c] = sB[32 + c];
    #pragma unroll 4
    for (int j = 0; j < 32; ++j) {
        const float zj = z1[j];
        const float* wr = &sW2[j * 32];
        #pragma unroll
        for (int c = 0; c < 32; c += 4) {
            const float4 w = *(const float4*)(wr + c);
            z2[c]     = fmaf(zj, w.x, z2[c]);
            z2[c + 1] = fmaf(zj, w.y, z2[c + 1]);
            z2[c + 2] = fmaf(zj, w.z, z2[c + 2]);
            z2[c + 3] = fmaf(zj, w.w, z2[c + 3]);
        }
    }
    #pragma unroll
    for (int c = 0; c < 32; ++c) z2[c] = fmaxf(z2[c], 0.0f);

    float lo[ROUT];
    #pragma unroll
    for (int c = 0; c < ROUT; ++c) lo[c] = sB[64 + c];
    #pragma unroll
    for (int j = 0; j < 32; ++j) {
        const float zj = z2[j];
        #pragma unroll
        for (int c = 0; c < ROUT; ++c)
            lo[c] = fmaf(zj, sW3[j * ROUT + c], lo[c]);
    }
    if (ROUT == 4) {
        *(float4*)(out + (size_t)i * 4) = make_float4(lo[0], lo[1], lo[2], lo[3]);
    } else {
        #pragma unroll
        for (int c = 0; c < ROUT; ++c) out[(size_t)i * ROUT + c] = lo[c];
    }
}

// ---- generic fallback MLP (off-path for this problem) ----
__global__ __launch_bounds__(64) void mlp_kernel(
    const _Float16* __restrict__ emb,
    const float* __restrict__ W1, const float* __restrict__ b1,
    const float* __restrict__ W2, const float* __restrict__ b2,
    const float* __restrict__ W3, const float* __restrict__ b3,
    float* __restrict__ out, int n, int featdim, int rout)
{
    typedef _Float16 lf16x8 __attribute__((ext_vector_type(8)));
    extern __shared__ float smem[];
    float* sW1 = smem;
    float* sW2 = sW1 + featdim * 32;
    float* sW3 = sW2 + 1024;
    float* sB  = sW3 + 32 * rout;
    for (int k = threadIdx.x; k < featdim * 32; k += blockDim.x) sW1[k] = W1[k];
    for (int k = threadIdx.x; k < 1024;         k += blockDim.x) sW2[k] = W2[k];
    for (int k = threadIdx.x; k < 32 * rout;    k += blockDim.x) sW3[k] = W3[k];
    {
        int t = threadIdx.x;
        if (t < 32) {
            sB[t] = b1[t];
            if (t < rout) sB[64 + t] = b3[t];
        } else if (t < 64) {
            sB[t] = b2[t - 32];
        }
    }
    __syncthreads();

    int i = blockIdx.x * blockDim.x + threadIdx.x;
    if (i >= n) return;
    const _Float16* f = emb + (size_t)i * featdim;

    float z1[32];
    #pragma unroll
    for (int c = 0; c < 32; ++c) z1[c] = sB[c];
    for (int k = 0; k < featdim; k += 8) {
        lf16x8 fv = *(const lf16x8*)(f + k);
        #pragma unroll
        for (int kk = 0; kk < 8; ++kk) {
            const float xk = (float)fv[kk];
            const float* wr = &sW1[(k + kk) * 32];
            #pragma unroll
            for (int c = 0; c < 32; ++c) z1[c] = fmaf(xk, wr[c], z1[c]);
        }
    }
    #pragma unroll
    for (int c = 0; c < 32; ++c) z1[c] = fmaxf(z1[c], 0.0f);

    float z2[32];
    #pragma unroll
    for (int c = 0; c < 32; ++c) z2[c] = sB[32 + c];
    #pragma unroll
    for (int j = 0; j < 32; ++j) {
        const float zj = z1[j];
        const float* wr = &sW2[j * 32];
        #pragma unroll
        for (int c = 0; c < 32; ++c) z2[c] = fmaf(zj, wr[c], z2[c]);
    }
    #pragma unroll
    for (int c = 0; c < 32; ++c) z2[c] = fmaxf(z2[c], 0.0f);

    for (int c = 0; c < rout; ++c) {
        float lo = sB[64 + c];
        #pragma unroll
        for (int j = 0; j < 32; ++j) lo = fmaf(z2[j], sW3[j * rout + c], lo);
        out[(size_t)i * rout + c] = lo;
    }
}

extern "C" void kernel_launch(void* const* d_in, const int* in_sizes, int n_in,
                              void* d_out, int out_size, void* d_ws, size_t ws_size,
                              hipStream_t stream) {
    const float* h    = (const float*)d_in[0];
    const int*   l    = (const int*)d_in[1];
    const float* W_ih = (const float*)d_in[2];
    const float* W_hh = (const float*)d_in[3];
    const float* b_ih = (const float*)d_in[4];
    const float* b_hh = (const float*)d_in[5];
    const float* W1   = (const float*)d_in[6];
    const float* b1   = (const float*)d_in[7];
    const float* W2   = (const float*)d_in[8];
    const float* b2   = (const float*)d_in[9];
    const float* W3   = (const float*)d_in[10];
    const float* b3   = (const float*)d_in[11];
    float* out = (float*)d_out;

    const int nseq = in_sizes[1];               // N*R = 131072
    const int tmax = in_sizes[0] / nseq;        // 256
    const int rout = in_sizes[10] / 32;         // R = 4
    const int n    = nseq / rout;               // 32768
    const int featdim = rout * HDIM;            // 128

    // workspace layout: emb is f16 (8 MB)
    _Float16* emb = (_Float16*)d_ws;
    int* perm = (int*)((char*)d_ws + (size_t)nseq * HDIM * sizeof(_Float16));
    int* cnt  = perm + nseq;
    int* off  = cnt + NBINS;

    hipMemsetAsync(cnt, 0, NBINS * sizeof(int), stream);
    hist_kernel<<<64, 256, 0, stream>>>(l, cnt, nseq);
    scan_kernel<<<1, NBINS, 0, stream>>>(cnt, off);
    scatter_kernel<<<64, 256, 0, stream>>>(l, off, perm, nseq);

    // 16 seqs/wave, 1 wave/block: 8192 waves = 8/SIMD (hw max), desc order
    const int nblk = (nseq + 15) / 16;
    rnn_kernel<<<nblk, 64, 0, stream>>>(
        h, l, perm, W_ih, W_hh, b_ih, b_hh, emb, nseq, tmax);

    if (featdim == 128 && rout == 4) {
        mlp_spec_kernel<128, 4><<<(n + 255) / 256, 256, 0, stream>>>(
            emb, W1, b1, W2, b2, W3, b3, out, n);
    } else {
        const int smem_bytes =
            (featdim * 32 + 1024 + 32 * rout + 64 + 32) * sizeof(float);
        mlp_kernel<<<(n + 63) / 64, 64, smem_bytes, stream>>>(
            emb, W1, b1, W2, b2, W3, b3, out, n, featdim, rout);
    }
}